// Round 1
// baseline (8573.046 us; speedup 1.0000x reference)
//
#include <hip/hip_runtime.h>
#include <hip/hip_bf16.h>

typedef unsigned short ushort_t;
typedef __attribute__((ext_vector_type(8))) short short8;
typedef __attribute__((ext_vector_type(4))) float f32x4;

#define T_ 64
#define B_ 16
#define S_ 400
#define E_ 128
#define H_ 256
#define H2_ 512
#define DV_ 50000
#define VOC_ 50050
#define CAT_ 896

// ---- d_out float offsets
#define YP_SZ   ((size_t)T_*B_*VOC_)              // 51,251,200
#define HS_OFF  (YP_SZ)
#define WW_OFF  (HS_OFF + (size_t)T_*B_*H_)
#define CV_OFF  (WW_OFF + (size_t)T_*B_*S_)
// scratch carved out of the y_pred region (dead before the big GEMM runs):
#define ENCP_OFF   ((size_t)0)                    // [S*B][512] f32
#define CTXALL_OFF ((size_t)S_*B_*H2_)            // [T*B][512] f32

// ---- ws float offsets
#define WS_BAR     0        // int[1024] barrier slots
#define WS_ROWSUM  1024     // f32[1024]
#define WS_UCTX    2048     // f32[2][16][512]
#define WS_ESUM    18432    // f32[2][16][8]
#define WS_S1      18688    // f32[16][256]
#define WS_SWS     22784    // f32[16][512]
#define WS_HID     30976    // f32[16][256]
#define WS_COV     35072    // f32[16][400]
#define WS_EG      41472    // f32[16][400]
#define WS_G1      47872    // bf16[1024][256] (131072 floats of space)
#define WS_GV      178944   // f32[1024]
#define WS_MEMSET_FLOATS 18688

#define NBLK 128
#define NTHR 512

__device__ __forceinline__ float fsig(float x){ return 1.f/(1.f+__expf(-x)); }
__device__ __forceinline__ float ftanh(float x){ float e=__expf(2.f*x); return 1.f - 2.f/(e+1.f); }

// Device-wide barrier, one fresh counter slot per use (slots zeroed by memset each launch).
// Release on the add publishes this XCD's L2 (buffer_wbl2); acquire on the spin load
// invalidates stale L1/L2 lines before the post-barrier reads (agent-scope memory model).
__device__ __forceinline__ void gbar(int* bar, int slot){
  __syncthreads();
  if (threadIdx.x == 0){
    __hip_atomic_fetch_add(&bar[slot], 1, __ATOMIC_RELEASE, __HIP_MEMORY_SCOPE_AGENT);
    while (__hip_atomic_load(&bar[slot], __ATOMIC_ACQUIRE, __HIP_MEMORY_SCOPE_AGENT) < NBLK)
      __builtin_amdgcn_s_sleep(2);
  }
  __syncthreads();
}

// ---------------------------------------------------------------- prep
__global__ __launch_bounds__(512)
void prep_kernel(const float* inith, const float* initc, float* ws){
  int gid = blockIdx.x*512 + threadIdx.x;
  if (gid < B_*H_) ws[WS_HID + gid] = inith[gid];
  if (gid < B_*S_) ws[WS_COV + gid] = initc[gid];
}

// ---------------------------------------------------------------- enc_proj = enc @ W_h^T + b_attn
__global__ __launch_bounds__(256)
void encproj_kernel(const float* enc, const float* Wh, const float* battn, float* dout){
  __shared__ float As[64][33];
  __shared__ float Bs[128][33];
  int m0 = blockIdx.x*64, n0 = blockIdx.y*128;
  int tx = threadIdx.x & 15, ty = threadIdx.x >> 4;
  float acc[4][8] = {};
  for (int kt = 0; kt < 512; kt += 32){
    for (int l = threadIdx.x; l < 64*32; l += 256){
      int m = l>>5, k = l&31; As[m][k] = enc[(size_t)(m0+m)*H2_ + kt + k];
    }
    for (int l = threadIdx.x; l < 128*32; l += 256){
      int n = l>>5, k = l&31; Bs[n][k] = Wh[(size_t)(n0+n)*H2_ + kt + k];
    }
    __syncthreads();
    for (int k = 0; k < 32; ++k){
      float a[4], bv[8];
      #pragma unroll
      for (int i=0;i<4;++i) a[i] = As[ty+16*i][k];
      #pragma unroll
      for (int j=0;j<8;++j) bv[j] = Bs[tx+16*j][k];
      #pragma unroll
      for (int i=0;i<4;++i)
        #pragma unroll
        for (int j=0;j<8;++j) acc[i][j] += a[i]*bv[j];
    }
    __syncthreads();
  }
  #pragma unroll
  for (int i=0;i<4;++i)
    #pragma unroll
    for (int j=0;j<8;++j){
      int m = m0 + ty + 16*i, n = n0 + tx + 16*j;
      dout[ENCP_OFF + (size_t)m*H2_ + n] = acc[i][j] + battn[n];
    }
}

// ---------------------------------------------------------------- persistent scan
__global__ __launch_bounds__(NTHR)
void scan_kernel(const float* emb, const float* enc, const float* xm, const float* ym,
                 const float* Wih1, const float* Whh1, const float* bih1, const float* bhh1,
                 const float* Wih2, const float* Whh2, const float* bih2, const float* bhh2,
                 const float* Ws, const float* Wc, const float* Vat,
                 float* ws, float* dout)
{
  __shared__ __align__(16) float sWs_l[H2_];
  __shared__ __align__(16) float Vl[H2_];
  __shared__ __align__(16) float Wcl[H2_];
  __shared__ float es_l[64];
  int* bar     = (int*)ws;
  float* uctx  = ws + WS_UCTX;
  float* esump = ws + WS_ESUM;
  float* s1g   = ws + WS_S1;
  float* sWsg  = ws + WS_SWS;
  float* hidg  = ws + WS_HID;
  float* covg  = ws + WS_COV;
  float* eg    = ws + WS_EG;
  int blk = blockIdx.x, tid = threadIdx.x;
  if (tid < H2_){ Vl[tid] = Vat[tid]; Wcl[tid] = Wc[tid]; }
  int slot = 0;
  for (int t = 0; t < T_; ++t){
    // ---- P1: GRU1 -> s1   (blocks 0..31; task=(j0,b) j-major, kq splits K in 4)
    if (blk < 32){
      int gid = blk*NTHR + tid;
      int task = gid >> 2, kq = gid & 3;
      int j0 = task >> 4, b = task & 15;
      const float* x  = emb  + ((size_t)t*B_ + b)*E_;
      const float* hp = hidg + b*H_;
      float gxr=0,gxz=0,gxn=0,ghr=0,ghz=0,ghn=0;
      {
        const float* wr = Wih1 + (size_t)j0*E_ + kq*32;
        const float* wz = wr + (size_t)H_*E_;
        const float* wn = wz + (size_t)H_*E_;
        const float* xx = x + kq*32;
        #pragma unroll 8
        for (int i = 0; i < 32; ++i){ float xv = xx[i]; gxr += xv*wr[i]; gxz += xv*wz[i]; gxn += xv*wn[i]; }
      }
      {
        const float* wr = Whh1 + (size_t)j0*H_ + kq*64;
        const float* wz = wr + (size_t)H_*H_;
        const float* wn = wz + (size_t)H_*H_;
        const float* hh = hp + kq*64;
        #pragma unroll 8
        for (int i = 0; i < 64; ++i){ float hv = hh[i]; ghr += hv*wr[i]; ghz += hv*wz[i]; ghn += hv*wn[i]; }
      }
      float a0 = gxr+ghr, a1 = gxz+ghz, a2 = gxn, a3 = ghn;
      a0 += __shfl_xor(a0,1,4); a0 += __shfl_xor(a0,2,4);
      a1 += __shfl_xor(a1,1,4); a1 += __shfl_xor(a1,2,4);
      a2 += __shfl_xor(a2,1,4); a2 += __shfl_xor(a2,2,4);
      a3 += __shfl_xor(a3,1,4); a3 += __shfl_xor(a3,2,4);
      if (kq == 0){
        float r = fsig(a0 + bih1[j0] + bhh1[j0]);
        float z = fsig(a1 + bih1[H_+j0] + bhh1[H_+j0]);
        float n = ftanh(a2 + bih1[2*H_+j0] + r*(a3 + bhh1[2*H_+j0]));
        float hv = hidg[b*H_+j0];
        float ymv = ym[t*B_+b];
        float s1 = (1.f-z)*n + z*hv;
        s1 = ymv*s1 + (1.f-ymv)*hv;
        s1g[b*H_+j0] = s1;
      }
    }
    gbar(bar, slot++);
    // ---- P2: sWs = s1 @ Ws^T  (blocks 0..15; task=(k,b) k-major)
    if (blk < 16){
      int gid = blk*NTHR + tid;
      int k = gid >> 4, b = gid & 15;
      const float* s1 = s1g + b*H_;
      const float* w  = Ws + (size_t)k*H_;
      float acc = 0;
      #pragma unroll 8
      for (int j = 0; j < H_; ++j) acc += s1[j]*w[j];
      sWsg[b*H2_ + k] = acc;
    }
    gbar(bar, slot++);
    // ---- P3: scores+exp+uctx partials  (all 128 blocks; block=(b, slice of 50 rows))
    {
      int b = blk >> 3, sl = blk & 7;
      if (tid < H2_) sWs_l[tid] = sWsg[b*H2_ + tid];
      if (tid < 50){               // (a) waw_{t-1}, coverage update, covs[t]
        int r = sl*50 + tid;
        size_t ci = ((size_t)t*B_ + b)*S_ + r;
        if (t == 0){
          dout[CV_OFF + ci] = covg[b*S_ + r];
        } else {
          int pp = (t-1)&1;
          float es = 0;
          #pragma unroll
          for (int q = 0; q < 8; ++q) es += esump[pp*128 + b*8 + q];
          float waw = eg[b*S_ + r] / es;
          dout[WW_OFF + ((size_t)(t-1)*B_ + b)*S_ + r] = waw;
          float cv = covg[b*S_ + r] + waw;
          covg[b*S_ + r] = cv;
          dout[CV_OFF + ci] = cv;
        }
      }
      __syncthreads();
      int g = tid >> 3, lane8 = tid & 7;   // (b) 8 lanes per row, 64 k each
      if (g < 50){
        int r = sl*50 + g;
        const float4* ep4 = (const float4*)(dout + ENCP_OFF + ((size_t)r*B_ + b)*H2_) + lane8*16;
        float cv = covg[b*S_ + r];
        float acc = 0;
        int k0 = lane8*64;
        #pragma unroll 4
        for (int i = 0; i < 16; ++i){
          float4 e4 = ep4[i];
          int k = k0 + i*4;
          acc += ftanh(e4.x + sWs_l[k]   + cv*Wcl[k]  ) * Vl[k];
          acc += ftanh(e4.y + sWs_l[k+1] + cv*Wcl[k+1]) * Vl[k+1];
          acc += ftanh(e4.z + sWs_l[k+2] + cv*Wcl[k+2]) * Vl[k+2];
          acc += ftanh(e4.w + sWs_l[k+3] + cv*Wcl[k+3]) * Vl[k+3];
        }
        acc += __shfl_xor(acc,1,8); acc += __shfl_xor(acc,2,8); acc += __shfl_xor(acc,4,8);
        if (lane8 == 0){
          float xmv = xm[(size_t)r*B_ + b];
          float sc = (xmv == 0.f) ? -1e9f : xmv*acc;   // softmax w/o max-sub: |score|<~25, safe
          float e = __expf(sc);
          eg[b*S_ + r] = e;
          es_l[g] = e;
        }
      }
      __syncthreads();
      if (tid == 0){
        float s = 0;
        for (int q = 0; q < 50; ++q) s += es_l[q];
        esump[(t&1)*128 + b*8 + sl] = s;
      }
      {                            // (c) unnormalized ctx partial
        int k = tid;
        const float* encb = enc + ((size_t)(sl*50)*B_ + b)*H2_ + k;
        float acc = 0;
        #pragma unroll 5
        for (int ri = 0; ri < 50; ++ri) acc += es_l[ri] * encb[(size_t)ri*B_*H2_];
        atomicAdd(&uctx[(t&1)*(B_*H2_) + b*H2_ + k], acc);
      }
    }
    gbar(bar, slot++);
    // ---- P4: GRU2 -> hidden  (blocks 0..31; block 32 zeroes next uctx buffer)
    if (blk < 32){
      int gid = blk*NTHR + tid;
      int task = gid >> 2, kq = gid & 3;
      int j0 = task >> 4, b = task & 15;
      const float* uc  = uctx + (t&1)*(B_*H2_) + b*H2_;
      const float* s1p = s1g + b*H_;
      float gxr=0,gxz=0,gxn=0,ghr=0,ghz=0,ghn=0;
      {
        const float* wr = Wih2 + (size_t)j0*H2_ + kq*128;
        const float* wz = wr + (size_t)H_*H2_;
        const float* wn = wz + (size_t)H_*H2_;
        const float* cc = uc + kq*128;
        #pragma unroll 8
        for (int i = 0; i < 128; ++i){ float c = cc[i]; gxr += c*wr[i]; gxz += c*wz[i]; gxn += c*wn[i]; }
      }
      {
        const float* wr = Whh2 + (size_t)j0*H_ + kq*64;
        const float* wz = wr + (size_t)H_*H_;
        const float* wn = wz + (size_t)H_*H_;
        const float* ss = s1p + kq*64;
        #pragma unroll 8
        for (int i = 0; i < 64; ++i){ float sv = ss[i]; ghr += sv*wr[i]; ghz += sv*wz[i]; ghn += sv*wn[i]; }
      }
      gxr += __shfl_xor(gxr,1,4); gxr += __shfl_xor(gxr,2,4);
      gxz += __shfl_xor(gxz,1,4); gxz += __shfl_xor(gxz,2,4);
      gxn += __shfl_xor(gxn,1,4); gxn += __shfl_xor(gxn,2,4);
      ghr += __shfl_xor(ghr,1,4); ghr += __shfl_xor(ghr,2,4);
      ghz += __shfl_xor(ghz,1,4); ghz += __shfl_xor(ghz,2,4);
      ghn += __shfl_xor(ghn,1,4); ghn += __shfl_xor(ghn,2,4);
      if (kq == 0){
        float es = 0;
        #pragma unroll
        for (int q = 0; q < 8; ++q) es += esump[(t&1)*128 + b*8 + q];
        float inv = 1.f/es;
        float r = fsig(gxr*inv + bih2[j0] + ghr + bhh2[j0]);
        float z = fsig(gxz*inv + bih2[H_+j0] + ghz + bhh2[H_+j0]);
        float n = ftanh(gxn*inv + bih2[2*H_+j0] + r*(ghn + bhh2[2*H_+j0]));
        float s1v = s1p[j0];
        float ymv = ym[t*B_+b];
        float s2 = (1.f-z)*n + z*s1v;
        s2 = ymv*s2 + (1.f-ymv)*s1v;
        hidg[b*H_+j0] = s2;
        dout[HS_OFF + ((size_t)t*B_ + b)*H_ + j0] = s2;
        float* cta = dout + CTXALL_OFF + ((size_t)t*B_ + b)*H2_;
        cta[j0]      = uc[j0]*inv;
        cta[H_ + j0] = uc[H_ + j0]*inv;
      }
    } else if (blk == 32){
      float* un = uctx + ((t+1)&1)*(B_*H2_);
      for (int i = tid; i < B_*H2_; i += NTHR) un[i] = 0.f;
    }
    gbar(bar, slot++);
  }
  // flush waws[T-1]
  {
    int b = blk >> 3, sl = blk & 7;
    if (tid < 50){
      int r = sl*50 + tid;
      int pp = (T_-1)&1;
      float es = 0;
      #pragma unroll
      for (int q = 0; q < 8; ++q) es += esump[pp*128 + b*8 + q];
      dout[WW_OFF + ((size_t)(T_-1)*B_ + b)*S_ + r] = eg[b*S_ + r]/es;
    }
  }
}

// ---------------------------------------------------------------- G1 = tanh([hs|ctx|emb]@V1^T+b), g = sigmoid(...Wp)
__global__ __launch_bounds__(512)
void head_kernel(const float* emb, const float* V1w, const float* V1b,
                 const float* Wpw, const float* Wpb, float* dout, float* ws)
{
  __shared__ float hc[B_][CAT_];
  int t = blockIdx.x, tid = threadIdx.x;
  for (int i = tid; i < B_*CAT_; i += 512){
    int b = i / CAT_, k = i % CAT_;
    float v;
    if (k < H_)           v = dout[HS_OFF     + ((size_t)(t*B_+b))*H_  + k];
    else if (k < H_+H2_)  v = dout[CTXALL_OFF + ((size_t)(t*B_+b))*H2_ + (k-H_)];
    else                  v = emb[((size_t)(t*B_+b))*E_ + (k-H_-H2_)];
    hc[b][k] = v;
  }
  __syncthreads();
  __hip_bfloat16* G1 = (__hip_bfloat16*)(ws + WS_G1);
  int j = tid >> 1, half = tid & 1;
  const float* wv = V1w + (size_t)j*CAT_;
  float vb = V1b[j];
  for (int bb = 0; bb < 8; ++bb){
    int b = half*8 + bb;
    float acc = 0;
    #pragma unroll 8
    for (int k = 0; k < CAT_; ++k) acc += hc[b][k]*wv[k];
    G1[((size_t)(t*B_+b))*H_ + j] = __float2bfloat16(ftanh(acc + vb));
  }
  if (tid < B_){
    int b = tid; float acc = 0;
    for (int k = 0; k < CAT_; ++k) acc += hc[b][k]*Wpw[k];
    ws[WS_GV + t*B_ + b] = fsig(acc + Wpb[0]);
  }
}

// ---------------------------------------------------------------- logits GEMM (bf16 MFMA) + exp + rowsums
__global__ __launch_bounds__(256)
void gemm2_kernel(const ushort_t* G1, const float* V2w, const float* V2b,
                  float* dout, float* rowsum)
{
  __shared__ float rows_l[128];
  int tid = threadIdx.x;
  if (tid < 128) rows_l[tid] = 0.f;
  int m0 = blockIdx.y * 128;
  int n0 = blockIdx.x * 64;
  int lane = tid & 63, w = tid >> 6;
  int c16 = lane & 15, kg = lane >> 4;
  int col = n0 + w*16 + c16;
  int colc = col < DV_ ? col : DV_-1;
  bool valid = col < DV_;
  f32x4 acc[8] = {};
  const float* brow = V2w + (size_t)colc*H_;
  for (int ks = 0; ks < 8; ++ks){
    int k0 = ks*32 + kg*8;
    short8 bf;
    #pragma unroll
    for (int i = 0; i < 8; ++i){
      __hip_bfloat16 hb = __float2bfloat16(brow[k0+i]);
      union { __hip_bfloat16 h; short s; } u; u.h = hb;
      bf[i] = u.s;
    }
    #pragma unroll
    for (int mf = 0; mf < 8; ++mf){
      const short8* ap = (const short8*)(G1 + ((size_t)(m0 + mf*16 + c16))*H_ + k0);
      acc[mf] = __builtin_amdgcn_mfma_f32_16x16x32_bf16(*ap, bf, acc[mf], 0, 0, 0);
    }
  }
  float bias = valid ? V2b[colc] : 0.f;
  __syncthreads();
  #pragma unroll
  for (int mf = 0; mf < 8; ++mf){
    #pragma unroll
    for (int r = 0; r < 4; ++r){
      float v = valid ? __expf(acc[mf][r] + bias) : 0.f;
      int rloc = mf*16 + kg*4 + r;
      if (valid) dout[(size_t)(m0 + rloc)*VOC_ + col] = v;
      float s = v;
      s += __shfl_xor(s, 1, 16); s += __shfl_xor(s, 2, 16);
      s += __shfl_xor(s, 4, 16); s += __shfl_xor(s, 8, 16);
      if (c16 == 0) atomicAdd(&rows_l[rloc], s);
    }
  }
  __syncthreads();
  if (tid < 128) atomicAdd(&rowsum[m0 + tid], rows_l[tid]);
}

// ---------------------------------------------------------------- normalize + g, zero EXT region
__global__ __launch_bounds__(256)
void norm_kernel(float* dout, const float* ws){
  int row = blockIdx.x;
  float sc = ws[WS_GV + row] / ws[WS_ROWSUM + row];
  float2* y2 = (float2*)(dout + (size_t)row * VOC_);
  for (int i = threadIdx.x; i < VOC_/2; i += 256){
    float2 v = y2[i];
    int e0 = 2*i;
    v.x = (e0   < DV_) ? v.x*sc : 0.f;
    v.y = (e0+1 < DV_) ? v.y*sc : 0.f;
    y2[i] = v;
  }
}

// ---------------------------------------------------------------- pointer scatter
__global__ __launch_bounds__(256)
void scatter_kernel(float* dout, const float* ws, const int* xidx){
  int row = blockIdx.x; int b = row & 15;
  float g1 = 1.f - ws[WS_GV + row];
  const float* ww = dout + WW_OFF + (size_t)row*S_;
  float* y = dout + (size_t)row*VOC_;
  for (int s = threadIdx.x; s < S_; s += 256){
    atomicAdd(&y[xidx[(size_t)s*B_ + b]], g1*ww[s]);
  }
}

extern "C" void kernel_launch(void* const* d_in, const int* in_sizes, int n_in,
                              void* d_out, int out_size, void* d_ws, size_t ws_size,
                              hipStream_t stream)
{
  (void)in_sizes; (void)n_in; (void)out_size; (void)ws_size;
  const float* emb   = (const float*)d_in[0];
  const float* enc   = (const float*)d_in[1];
  const float* inith = (const float*)d_in[2];
  const float* xmask = (const float*)d_in[3];
  const float* ymask = (const float*)d_in[4];
  const int*   xidx  = (const int*)d_in[5];
  const float* initc = (const float*)d_in[7];
  const float* Wh    = (const float*)d_in[8];
  const float* Wss   = (const float*)d_in[9];
  const float* Wc    = (const float*)d_in[10];
  const float* battn = (const float*)d_in[11];
  const float* Vat   = (const float*)d_in[12];
  const float* Wih1  = (const float*)d_in[13];
  const float* Whh1  = (const float*)d_in[14];
  const float* bih1  = (const float*)d_in[15];
  const float* bhh1  = (const float*)d_in[16];
  const float* Wih2  = (const float*)d_in[17];
  const float* Whh2  = (const float*)d_in[18];
  const float* bih2  = (const float*)d_in[19];
  const float* bhh2  = (const float*)d_in[20];
  const float* V1w   = (const float*)d_in[21];
  const float* V1b   = (const float*)d_in[22];
  const float* V2w   = (const float*)d_in[23];
  const float* V2b   = (const float*)d_in[24];
  const float* Wpw   = (const float*)d_in[25];
  const float* Wpb   = (const float*)d_in[26];
  float* out = (float*)d_out;
  float* ws  = (float*)d_ws;

  hipMemsetAsync(d_ws, 0, (size_t)WS_MEMSET_FLOATS*4, stream);
  prep_kernel<<<32, 512, 0, stream>>>(inith, initc, ws);
  encproj_kernel<<<dim3(100,4), 256, 0, stream>>>(enc, Wh, battn, out);
  scan_kernel<<<NBLK, NTHR, 0, stream>>>(emb, enc, xmask, ymask,
      Wih1, Whh1, bih1, bhh1, Wih2, Whh2, bih2, bhh2, Wss, Wc, Vat, ws, out);
  head_kernel<<<64, 512, 0, stream>>>(emb, V1w, V1b, Wpw, Wpb, out, ws);
  gemm2_kernel<<<dim3(782,8), 256, 0, stream>>>((const ushort_t*)(ws + WS_G1), V2w, V2b, out, ws + WS_ROWSUM);
  norm_kernel<<<1024, 256, 0, stream>>>(out, ws);
  scatter_kernel<<<1024, 256, 0, stream>>>(out, ws, xidx);
}